// Round 7
// baseline (1573.382 us; speedup 1.0000x reference)
//
#include <hip/hip_runtime.h>

#define HIDDEN 448

typedef __attribute__((ext_vector_type(8))) short short8;
typedef __attribute__((ext_vector_type(4))) float f32x4;

// ---------- bf16 helpers (raw u16 storage, f32 math) ----------
__device__ __forceinline__ unsigned short f2bf(float f) {
    unsigned int u = __float_as_uint(f);
    u = (u + 0x7fffu + ((u >> 16) & 1u)) >> 16;   // RTNE
    return (unsigned short)u;
}
__device__ __forceinline__ float bf2f(unsigned short h) {
    return __uint_as_float(((unsigned int)h) << 16);
}
__device__ __forceinline__ float lo_bf(unsigned int u) { return __uint_as_float(u << 16); }
__device__ __forceinline__ float hi_bf(unsigned int u) { return __uint_as_float(u & 0xffff0000u); }
// one-instruction RTNE pack of two f32 -> 2x bf16 (lo = a, hi = b)
__device__ __forceinline__ unsigned int cvt_pk_bf16(float a, float b) {
    unsigned int r;
    asm("v_cvt_pk_bf16_f32 %0, %1, %2" : "=v"(r) : "v"(a), "v"(b));
    return r;
}

// ================= prep kernels =================
// out[448][512] bf16: k<Ktop -> Wtop[k][n]; Ktop<=k<64 -> 0; k>=64 -> Wbot[k-64][n]
__global__ __launch_bounds__(256) void prep_wcat_kernel(
    const float* __restrict__ Wtop, int Ktop, const float* __restrict__ Wbot,
    unsigned short* __restrict__ out)
{
    const int idx = blockIdx.x * 256 + threadIdx.x;
    if (idx >= 448 * 512) return;
    const int n = idx >> 9, k = idx & 511;
    float v = 0.0f;
    if (k < Ktop) v = Wtop[k * HIDDEN + n];
    else if (k >= 64) v = Wbot[(k - 64) * HIDDEN + n];
    out[idx] = f2bf(v);
}

// out[M][64] bf16: k<K -> A[row][k] else 0
__global__ __launch_bounds__(256) void prep_apad_kernel(
    const float* __restrict__ A, int K, unsigned short* __restrict__ out, int total)
{
    const int idx = blockIdx.x * 256 + threadIdx.x;
    if (idx >= total) return;
    const int row = idx >> 6, k = idx & 63;
    out[idx] = (k < K) ? f2bf(A[(long)row * K + k]) : (unsigned short)0;
}

// ================= MFMA GEMM =================
// out[M][448] = relu( [Apad | deq(A2q)*A2s] @ BT^T + bias? ), bf16 MFMA, f32 acc.
// Apad: [M][64] bf16 (K-steps 0..1). A2q: [M][448] u8 + per-row scale A2s (K-steps
// 2..15) or null. BT: [448 n][512 k] bf16. nsteps = 2 (Apad only) or 16.
__global__ __launch_bounds__(256) void gemm_mfma_kernel(
    const unsigned short* __restrict__ Apad,
    const unsigned char* __restrict__ A2q,
    const float* __restrict__ A2s,
    const unsigned short* __restrict__ BT,
    const float* __restrict__ bias,
    unsigned short* __restrict__ out,
    int M, int nsteps)
{
    __shared__ unsigned short As[128 * 40];   // [row][kpad=40], 80B stride
    __shared__ unsigned short Bs[112 * 40];   // [col][kpad=40]

    const int tid = threadIdx.x;
    const int lane = tid & 63;
    const int wv = tid >> 6;                  // wave id 0..3 (M split)
    const int row0 = blockIdx.y * 128;
    const int col0 = blockIdx.x * 112;

    f32x4 acc[2][7] = {};

    for (int s = 0; s < nsteps; ++s) {
        const bool seg1 = (s < 2);
        // ---- stage A: 512 units (row 0..127, quarter 0..3), 16B each
        #pragma unroll
        for (int i = 0; i < 2; ++i) {
            const int u = tid + 256 * i;
            const int row = u >> 2, q = u & 3;
            const int grow = row0 + row;
            uint4 v = make_uint4(0, 0, 0, 0);
            if (grow < M) {
                if (seg1) {
                    v = *(const uint4*)(Apad + (size_t)grow * 64 + s * 32 + q * 8);
                } else {
                    const uint2 b8 = *(const uint2*)(A2q + (size_t)grow * HIDDEN
                                                     + (s - 2) * 32 + q * 8);
                    const float sc = A2s[grow];
                    // v_cvt_f32_ubyteN (pattern-matched) + mul + v_cvt_pk_bf16_f32
                    v.x = cvt_pk_bf16((float)(b8.x & 255u) * sc,
                                      (float)((b8.x >> 8) & 255u) * sc);
                    v.y = cvt_pk_bf16((float)((b8.x >> 16) & 255u) * sc,
                                      (float)(b8.x >> 24) * sc);
                    v.z = cvt_pk_bf16((float)(b8.y & 255u) * sc,
                                      (float)((b8.y >> 8) & 255u) * sc);
                    v.w = cvt_pk_bf16((float)((b8.y >> 16) & 255u) * sc,
                                      (float)(b8.y >> 24) * sc);
                }
            }
            *(uint4*)&As[row * 40 + q * 8] = v;
        }
        // ---- stage B: 448 units (col 0..111, quarter 0..3), global col = col0+col
        #pragma unroll
        for (int i = 0; i < 2; ++i) {
            const int u = tid + 256 * i;
            if (u < 448) {
                const int col = u >> 2, q = u & 3;
                const uint4 v = *(const uint4*)(BT + (size_t)(col0 + col) * 512
                                                + s * 32 + q * 8);
                *(uint4*)&Bs[col * 40 + q * 8] = v;
            }
        }
        __syncthreads();

        const int g16 = (lane >> 4) * 8;   // k sub-block (elements)
        const int rr = lane & 15;
        short8 av[2], bv[7];
        #pragma unroll
        for (int m = 0; m < 2; ++m)
            av[m] = *(const short8*)&As[(wv * 32 + m * 16 + rr) * 40 + g16];
        #pragma unroll
        for (int n = 0; n < 7; ++n)
            bv[n] = *(const short8*)&Bs[(n * 16 + rr) * 40 + g16];
        #pragma unroll
        for (int m = 0; m < 2; ++m)
            #pragma unroll
            for (int n = 0; n < 7; ++n)
                acc[m][n] = __builtin_amdgcn_mfma_f32_16x16x32_bf16(
                    av[m], bv[n], acc[m][n], 0, 0, 0);
        __syncthreads();
    }

    // epilogue: D row = (lane>>4)*4 + j, col = lane&15  (m89-verified)
    const int r4 = (lane >> 4) << 2;
    const int cc = lane & 15;
    #pragma unroll
    for (int n = 0; n < 7; ++n) {
        const int col = col0 + n * 16 + cc;
        const float bsv = bias ? bias[col] : 0.0f;
        #pragma unroll
        for (int m = 0; m < 2; ++m) {
            #pragma unroll
            for (int j = 0; j < 4; ++j) {
                const int row = row0 + wv * 32 + m * 16 + r4 + j;
                if (row < M) {
                    const float v = fmaxf(acc[m][n][j] + bsv, 0.0f);
                    out[(size_t)row * HIDDEN + col] = f2bf(v);
                }
            }
        }
    }
}

// ================= gather (q8, vectorized) =================
// bf16 msg -> per-row-scaled uint8. One wave per row; lanes 0..55 each own one
// 8-element (16B) chunk; 6 uint4 loads + unpack replace 42 scalar loads.
__global__ __launch_bounds__(256) void gather_q8_kernel(
    const unsigned short* __restrict__ msg, const int* __restrict__ graph,
    unsigned char* __restrict__ outq, float* __restrict__ outs, int M)
{
    const int row = blockIdx.x * 4 + (threadIdx.x >> 6);
    const int lane = threadIdx.x & 63;
    if (row >= M) return;
    const int* g = graph + (long)row * 6;   // wave-uniform -> s_loads
    float acc[8] = {};
    if (lane < 56) {
        #pragma unroll
        for (int j = 0; j < 6; ++j) {
            const uint4 v = *((const uint4*)(msg + (size_t)g[j] * HIDDEN) + lane);
            acc[0] += lo_bf(v.x); acc[1] += hi_bf(v.x);
            acc[2] += lo_bf(v.y); acc[3] += hi_bf(v.y);
            acc[4] += lo_bf(v.z); acc[5] += hi_bf(v.z);
            acc[6] += lo_bf(v.w); acc[7] += hi_bf(v.w);
        }
    }
    float mx = 0.0f;   // values are post-relu, >= 0; idle lanes contribute 0
    #pragma unroll
    for (int u = 0; u < 8; ++u) mx = fmaxf(mx, acc[u]);
    #pragma unroll
    for (int off = 32; off >= 1; off >>= 1) mx = fmaxf(mx, __shfl_xor(mx, off));
    const float inv = (mx > 0.0f) ? (255.0f / mx) : 0.0f;
    if (lane < 56) {
        unsigned int b[8];
        #pragma unroll
        for (int u = 0; u < 8; ++u)
            b[u] = __float2uint_rn(fminf(acc[u] * inv, 255.0f));
        uint2 o;
        o.x = b[0] | (b[1] << 8) | (b[2] << 16) | (b[3] << 24);
        o.y = b[4] | (b[5] << 8) | (b[6] << 16) | (b[7] << 24);
        *((uint2*)(outq + (size_t)row * HIDDEN) + lane) = o;
    }
    if (lane == 0) outs[row] = mx * (1.0f / 255.0f);
}

// ================= tail kernels =================
__global__ void segmean_kernel(
    const unsigned short* __restrict__ ah, const int* __restrict__ mol_idx,
    float* __restrict__ out, int n_atoms)
{
    const int m = blockIdx.x;
    const int c = threadIdx.x;
    int l = 0, r = n_atoms;
    while (l < r) { const int mid = (l + r) >> 1; if (mol_idx[mid] < m) l = mid + 1; else r = mid; }
    const int start = l;
    r = n_atoms;
    while (l < r) { const int mid = (l + r) >> 1; if (mol_idx[mid] < m + 1) l = mid + 1; else r = mid; }
    const int end = l;
    float acc = 0.0f;
    for (int a = start; a < end; ++a) acc += bf2f(ah[(long)a * HIDDEN + c]);
    out[(long)m * HIDDEN + c] = acc / fmaxf((float)(end - start), 1.0f);
}

__global__ __launch_bounds__(256) void fill_kernel(float* __restrict__ out, int n, float val)
{
    const int i = blockIdx.x * 256 + threadIdx.x;
    if (i < n) out[i] = val;
}

// ================= launch =================
extern "C" void kernel_launch(void* const* d_in, const int* in_sizes, int n_in,
                              void* d_out, int out_size, void* d_ws, size_t ws_size,
                              hipStream_t stream)
{
    const float* fatoms = (const float*)d_in[0];
    const float* fbonds = (const float*)d_in[1];
    const float* W_i    = (const float*)d_in[2];
    const float* W_h    = (const float*)d_in[3];
    const float* W_o    = (const float*)d_in[4];
    const float* b_o    = (const float*)d_in[5];
    const int*   agraph = (const int*)d_in[6];
    const int*   bgraph = (const int*)d_in[7];
    const int*   mol_idx= (const int*)d_in[8];

    const int n_atoms = in_sizes[0] / 38;          // 80000
    const int n_bonds = in_sizes[1] / 49;          // 160001
    const int n_mols  = out_size / HIDDEN;         // 4000

    const size_t eW  = (size_t)448 * 512;          // cat-weight elems
    const size_t eFb = (size_t)n_bonds * 64;       // padded fbonds elems
    const size_t eFa = (size_t)n_atoms * 64;       // padded fatoms elems
    const size_t nbX = (size_t)n_bonds * HIDDEN;   // message elems
    const size_t nbQ = (size_t)n_bonds * HIDDEN;   // u8 nei bytes
    // bytes: bf16 buffers + u8 nei + f32 scales  (~247.3 MB; ws = 256 MiB)
    const size_t need = 2 * (2 * eW + eFb + eFa + nbX) + nbQ + (size_t)n_bonds * 4;

    const dim3 blk(256);

    if (ws_size >= need) {
        unsigned short* WhcatT  = (unsigned short*)d_ws;
        unsigned short* WocatT  = WhcatT + eW;
        unsigned short* fbondsP = WocatT + eW;
        unsigned short* fatomsP = fbondsP + eFb;
        unsigned short* X       = fatomsP + eFa;        // bf16 message
        unsigned char*  NQ      = (unsigned char*)(X + nbX);  // u8 nei (8B-aligned)
        float*          NS      = (float*)(NQ + nbQ);   // per-row scales

        const int wblocks = (448 * 512 + 255) / 256;
        hipLaunchKernelGGL(prep_wcat_kernel, dim3(wblocks), blk, 0, stream,
                           W_i, 49, W_h, WhcatT);
        hipLaunchKernelGGL(prep_wcat_kernel, dim3(wblocks), blk, 0, stream,
                           W_o, 38, W_o + 38 * HIDDEN, WocatT);
        hipLaunchKernelGGL(prep_apad_kernel, dim3(((int)eFb + 255) / 256), blk, 0, stream,
                           fbonds, 49, fbondsP, (int)eFb);
        hipLaunchKernelGGL(prep_apad_kernel, dim3(((int)eFa + 255) / 256), blk, 0, stream,
                           fatoms, 38, fatomsP, (int)eFa);

        const dim3 gB(4, (n_bonds + 127) / 128);
        const dim3 gA(4, (n_atoms + 127) / 128);

        // message = relu(fbonds @ W_i)
        hipLaunchKernelGGL(gemm_mfma_kernel, gB, blk, 0, stream,
                           fbondsP, (const unsigned char*)nullptr, (const float*)nullptr,
                           WhcatT, (const float*)nullptr, X, n_bonds, 2);
        // 4 iterations: nei = q8(gather6(message)); message = relu(fbonds@W_i + nei@W_h)
        for (int it = 0; it < 4; ++it) {
            hipLaunchKernelGGL(gather_q8_kernel, dim3((n_bonds + 3) / 4), blk, 0, stream,
                               X, bgraph, NQ, NS, n_bonds);
            hipLaunchKernelGGL(gemm_mfma_kernel, gB, blk, 0, stream,
                               fbondsP, NQ, NS, WhcatT, (const float*)nullptr, X, n_bonds, 16);
        }
        // atom readout
        hipLaunchKernelGGL(gather_q8_kernel, dim3((n_atoms + 3) / 4), blk, 0, stream,
                           X, agraph, NQ, NS, n_atoms);
        hipLaunchKernelGGL(gemm_mfma_kernel, gA, blk, 0, stream,
                           fatomsP, NQ, NS, WocatT, b_o, X, n_atoms, 16);
        hipLaunchKernelGGL(segmean_kernel, dim3(n_mols), dim3(HIDDEN), 0, stream,
                           X, mol_idx, (float*)d_out, n_atoms);
    } else {
        // diagnostic: absmax = 2272 + ws_MiB
        const float val = -(float)((double)ws_size / (1024.0 * 1024.0));
        hipLaunchKernelGGL(fill_kernel, dim3((out_size + 255) / 256), blk, 0, stream,
                           (float*)d_out, out_size, val);
    }
}

// Round 8
// 1087.084 us; speedup vs baseline: 1.4473x; 1.4473x over previous
//
#include <hip/hip_runtime.h>

#define HIDDEN 448

typedef __attribute__((ext_vector_type(8))) short short8;
typedef __attribute__((ext_vector_type(4))) float f32x4;

// ---------- bf16 helpers ----------
__device__ __forceinline__ unsigned short f2bf(float f) {
    unsigned int u = __float_as_uint(f);
    u = (u + 0x7fffu + ((u >> 16) & 1u)) >> 16;   // RTNE
    return (unsigned short)u;
}
__device__ __forceinline__ float bf2f(unsigned short h) {
    return __uint_as_float(((unsigned int)h) << 16);
}
// one-instruction RTNE pack of two f32 -> 2x bf16 (lo = a, hi = b)
__device__ __forceinline__ unsigned int cvt_pk_bf16(float a, float b) {
    unsigned int r;
    asm("v_cvt_pk_bf16_f32 %0, %1, %2" : "=v"(r) : "v"(a), "v"(b));
    return r;
}
// async global->LDS, 16B per lane (wave-uniform LDS base + lane*16)
__device__ __forceinline__ void async16(void* lds, const void* g) {
    __builtin_amdgcn_global_load_lds(
        (const __attribute__((address_space(1))) unsigned int*)g,
        (__attribute__((address_space(3))) unsigned int*)lds, 16, 0, 0);
}

// ================= prep kernels (outputs chunk-swizzled: k ^= (row&3)<<3) =====
// BT[448 n][512 k]: k<Ktop -> Wtop[k][n]; Ktop<=k<64 -> 0; k>=64 -> Wbot[k-64][n]
__global__ __launch_bounds__(256) void prep_wcat_kernel(
    const float* __restrict__ Wtop, int Ktop, const float* __restrict__ Wbot,
    unsigned short* __restrict__ out)
{
    const int idx = blockIdx.x * 256 + threadIdx.x;
    if (idx >= 448 * 512) return;
    const int n = idx >> 9, k = idx & 511;
    float v = 0.0f;
    if (k < Ktop) v = Wtop[k * HIDDEN + n];
    else if (k >= 64) v = Wbot[(k - 64) * HIDDEN + n];
    out[(size_t)n * 512 + (k ^ ((n & 3) << 3))] = f2bf(v);
}

// Apad[Mpad][64]: k<K and row<Mreal -> A[row][k] else 0
__global__ __launch_bounds__(256) void prep_apad_kernel(
    const float* __restrict__ A, int K, unsigned short* __restrict__ out,
    int Mreal, int total)
{
    const int idx = blockIdx.x * 256 + threadIdx.x;
    if (idx >= total) return;
    const int row = idx >> 6, k = idx & 63;
    const float v = (row < Mreal && k < K) ? A[(size_t)row * K + k] : 0.0f;
    out[(size_t)row * 64 + (k ^ ((row & 3) << 3))] = f2bf(v);
}

// ================= MFMA GEMM =================
// out = relu( [Apad | A2] @ BT^T + bias? ).  Tile 64 rows x 448 cols, 8 waves
// (2M x 4N).  All staging via global_load_lds (sources pre-swizzled).
// OUTQ=1: write q8 X + per-row scale.  OUTQ=0: write bf16 (outh may alias A2).
template<int OUTQ>
__global__ __launch_bounds__(512, 4) void gemm_mfma_kernel(
    const unsigned short* __restrict__ Apad,
    const unsigned short* A2,
    const unsigned short* __restrict__ BT,
    const float* __restrict__ bias,
    unsigned short* outh,
    unsigned char* __restrict__ outq,
    float* __restrict__ outs,
    int M, int nsteps)
{
    __shared__ __align__(16) unsigned char smem[33792];
    unsigned short* As = (unsigned short*)smem;            // [64][32] linear
    unsigned short* Bs = (unsigned short*)(smem + 4096);   // [448][32] linear
    float* rmaxbuf = (float*)(smem + 32768);               // [64][4]

    const int tid = threadIdx.x, lane = tid & 63, wv = tid >> 6;
    const int row0 = blockIdx.x * 64;
    const int wrow = (wv & 1) * 32;        // M-half of this wave
    const int wcol = (wv >> 1) * 112;      // N-quarter of this wave
    const int rr = lane & 15, ch = lane >> 4;
    const int lrow = lane >> 2, lq = lane & 3;   // staging decomposition

    f32x4 acc[2][7] = {};

    for (int s = 0; s < nsteps; ++s) {
        // ---- B staging: 28 x 1KB chunks (16 cols x 64B each)
        #pragma unroll
        for (int i = 0; i < 4; ++i) {
            const int t = wv + 8 * i;
            if (t < 28)
                async16(Bs + t * 512 + lane * 8,
                        BT + (size_t)(t * 16 + lrow) * 512 + s * 32 + lq * 8);
        }
        // ---- A staging: 4 x 1KB chunks (waves 4..7)
        if (wv >= 4) {
            const int a = wv - 4;
            const int grow = row0 + a * 16 + lrow;
            const unsigned short* src = (s < 2)
                ? Apad + (size_t)grow * 64 + s * 32 + lq * 8
                : A2 + (size_t)grow * HIDDEN + (s - 2) * 32 + lq * 8;
            async16(As + a * 512 + lane * 8, src);
        }
        __syncthreads();

        short8 av[2];
        #pragma unroll
        for (int m = 0; m < 2; ++m) {
            const int r = wrow + m * 16 + rr;
            av[m] = *(const short8*)&As[r * 32 + ((ch ^ (r & 3)) << 3)];
        }
        #pragma unroll
        for (int n = 0; n < 7; ++n) {
            const int cl = wcol + n * 16 + rr;
            const short8 bv = *(const short8*)&Bs[cl * 32 + ((ch ^ (cl & 3)) << 3)];
            #pragma unroll
            for (int m = 0; m < 2; ++m)
                acc[m][n] = __builtin_amdgcn_mfma_f32_16x16x32_bf16(
                    av[m], bv, acc[m][n], 0, 0, 0);
        }
        __syncthreads();
    }

    const int r4 = ch << 2;

    if (OUTQ) {
        // per-lane row max over this wave's 7 n-cols (relu clamps at 0)
        float rpm[2][4];
        #pragma unroll
        for (int m = 0; m < 2; ++m)
            #pragma unroll
            for (int j = 0; j < 4; ++j) {
                float mx = 0.0f;
                #pragma unroll
                for (int n = 0; n < 7; ++n) mx = fmaxf(mx, acc[m][n][j]);
                rpm[m][j] = mx;
            }
        // reduce across the 16 cc-lanes (same rows)
        #pragma unroll
        for (int off = 1; off < 16; off <<= 1)
            #pragma unroll
            for (int m = 0; m < 2; ++m)
                #pragma unroll
                for (int j = 0; j < 4; ++j)
                    rpm[m][j] = fmaxf(rpm[m][j], __shfl_xor(rpm[m][j], off));
        // cross-wave (4 N-waves) via LDS
        if (rr == 0)
            #pragma unroll
            for (int m = 0; m < 2; ++m)
                #pragma unroll
                for (int j = 0; j < 4; ++j)
                    rmaxbuf[(wrow + m * 16 + r4 + j) * 4 + (wv >> 1)] = rpm[m][j];
        __syncthreads();
        float inv[2][4];
        #pragma unroll
        for (int m = 0; m < 2; ++m)
            #pragma unroll
            for (int j = 0; j < 4; ++j) {
                const int rl = wrow + m * 16 + r4 + j;
                const float mx = fmaxf(fmaxf(rmaxbuf[rl * 4 + 0], rmaxbuf[rl * 4 + 1]),
                                       fmaxf(rmaxbuf[rl * 4 + 2], rmaxbuf[rl * 4 + 3]));
                inv[m][j] = (mx > 0.0f) ? (255.0f / mx) : 0.0f;
                if (wv < 2 && rr == 0 && row0 + rl < M)
                    outs[row0 + rl] = mx * (1.0f / 255.0f);
            }
        // quantize into LDS (overlay on As/Bs; all ds_reads done at loop's end)
        unsigned char* q8 = smem;
        #pragma unroll
        for (int m = 0; m < 2; ++m)
            #pragma unroll
            for (int j = 0; j < 4; ++j) {
                const int rl = wrow + m * 16 + r4 + j;
                #pragma unroll
                for (int n = 0; n < 7; ++n) {
                    const float v = fmaxf(acc[m][n][j], 0.0f);
                    q8[rl * 448 + wcol + n * 16 + rr] =
                        (unsigned char)__float2uint_rn(fminf(v * inv[m][j], 255.0f));
                }
            }
        __syncthreads();
        // coalesced copy-out: 1792 x uint4
        #pragma unroll
        for (int i = 0; i < 4; ++i) {
            const int u = tid + 512 * i;
            if (u < 1792 && row0 + u / 28 < M)
                ((uint4*)(outq + (size_t)row0 * 448))[u] = ((const uint4*)q8)[u];
        }
    } else {
        #pragma unroll
        for (int n = 0; n < 7; ++n) {
            const int col = wcol + n * 16 + rr;
            const float bsv = bias ? bias[col] : 0.0f;
            #pragma unroll
            for (int m = 0; m < 2; ++m)
                #pragma unroll
                for (int j = 0; j < 4; ++j) {
                    const int row = row0 + wrow + m * 16 + r4 + j;
                    if (row < M)
                        outh[(size_t)row * HIDDEN + col] =
                            f2bf(fmaxf(acc[m][n][j] + bsv, 0.0f));
                }
        }
    }
}

// ================= gather: q8 msg -> bf16 nei (chunk-swizzled) =================
// One wave per row; lanes 0..55 own one 8-elem chunk.  6 uniform neighbor rows.
__global__ __launch_bounds__(256) void gather_deq_kernel(
    const unsigned char* __restrict__ Xq, const float* __restrict__ Xs,
    const int* __restrict__ graph,
    unsigned short* __restrict__ nei, int M)
{
    const int row = blockIdx.x * 4 + (threadIdx.x >> 6);
    const int lane = threadIdx.x & 63;
    if (row >= M || lane >= 56) return;
    const int* g = graph + (size_t)row * 6;   // wave-uniform -> scalar loads
    float acc[8] = {};
    #pragma unroll
    for (int j = 0; j < 6; ++j) {
        const int gj = g[j];
        const float s = Xs[gj];
        const uint2 b = *((const uint2*)(Xq + (size_t)gj * HIDDEN) + lane);
        acc[0] += (float)(b.x & 255u) * s;
        acc[1] += (float)((b.x >> 8) & 255u) * s;
        acc[2] += (float)((b.x >> 16) & 255u) * s;
        acc[3] += (float)(b.x >> 24) * s;
        acc[4] += (float)(b.y & 255u) * s;
        acc[5] += (float)((b.y >> 8) & 255u) * s;
        acc[6] += (float)((b.y >> 16) & 255u) * s;
        acc[7] += (float)(b.y >> 24) * s;
    }
    uint4 o;
    o.x = cvt_pk_bf16(acc[0], acc[1]);
    o.y = cvt_pk_bf16(acc[2], acc[3]);
    o.z = cvt_pk_bf16(acc[4], acc[5]);
    o.w = cvt_pk_bf16(acc[6], acc[7]);
    const int c = lane ^ (row & 3);   // pre-swizzle for GEMM LDS staging
    *((uint4*)(nei + (size_t)row * HIDDEN) + c) = o;
}

// ================= tail kernels =================
__global__ void segmean_kernel(
    const unsigned short* __restrict__ ah, const int* __restrict__ mol_idx,
    float* __restrict__ out, int n_atoms)
{
    const int m = blockIdx.x;
    const int c = threadIdx.x;
    int l = 0, r = n_atoms;
    while (l < r) { const int mid = (l + r) >> 1; if (mol_idx[mid] < m) l = mid + 1; else r = mid; }
    const int start = l;
    r = n_atoms;
    while (l < r) { const int mid = (l + r) >> 1; if (mol_idx[mid] < m + 1) l = mid + 1; else r = mid; }
    const int end = l;
    float acc = 0.0f;
    for (int a = start; a < end; ++a) acc += bf2f(ah[(size_t)a * HIDDEN + c]);
    out[(size_t)m * HIDDEN + c] = acc / fmaxf((float)(end - start), 1.0f);
}

__global__ __launch_bounds__(256) void fill_kernel(float* __restrict__ out, int n, float val)
{
    const int i = blockIdx.x * 256 + threadIdx.x;
    if (i < n) out[i] = val;
}

// ================= launch =================
extern "C" void kernel_launch(void* const* d_in, const int* in_sizes, int n_in,
                              void* d_out, int out_size, void* d_ws, size_t ws_size,
                              hipStream_t stream)
{
    const float* fatoms = (const float*)d_in[0];
    const float* fbonds = (const float*)d_in[1];
    const float* W_i    = (const float*)d_in[2];
    const float* W_h    = (const float*)d_in[3];
    const float* W_o    = (const float*)d_in[4];
    const float* b_o    = (const float*)d_in[5];
    const int*   agraph = (const int*)d_in[6];
    const int*   bgraph = (const int*)d_in[7];
    const int*   mol_idx= (const int*)d_in[8];

    const int n_atoms = in_sizes[0] / 38;          // 80000
    const int n_bonds = in_sizes[1] / 49;          // 160001
    const int n_mols  = out_size / HIDDEN;         // 4000

    const int Mb_b = (n_bonds + 63) & ~63;         // 160064
    const int Mb_a = (n_atoms + 63) & ~63;         // 80000

    const size_t eW  = (size_t)448 * 512;          // cat-weight elems
    const size_t eFb = (size_t)Mb_b * 64;
    const size_t eFa = (size_t)Mb_a * 64;
    const size_t eX  = (size_t)Mb_b * HIDDEN;      // q8 bytes / bf16 elems

    // bytes (~247.4 MB; ws = 256 MiB)
    const size_t need = 2 * eW * 2 + eFb * 2 + eFa * 2 + eX /*q8*/ +
                        (size_t)Mb_b * 4 /*scales*/ + eX * 2 /*nei bf16*/;

    const dim3 blk(256);

    if (ws_size >= need) {
        unsigned short* WhcatT  = (unsigned short*)d_ws;
        unsigned short* WocatT  = WhcatT + eW;
        unsigned short* fbondsP = WocatT + eW;
        unsigned short* fatomsP = fbondsP + eFb;
        unsigned char*  Xq      = (unsigned char*)(fatomsP + eFa);
        float*          Xs      = (float*)(Xq + eX);
        unsigned short* nei     = (unsigned short*)(Xs + Mb_b);

        const int wblocks = (448 * 512 + 255) / 256;
        hipLaunchKernelGGL(prep_wcat_kernel, dim3(wblocks), blk, 0, stream,
                           W_i, 49, W_h, WhcatT);
        hipLaunchKernelGGL(prep_wcat_kernel, dim3(wblocks), blk, 0, stream,
                           W_o, 38, W_o + 38 * HIDDEN, WocatT);
        hipLaunchKernelGGL(prep_apad_kernel, dim3(((int)eFb + 255) / 256), blk, 0, stream,
                           fbonds, 49, fbondsP, n_bonds, (int)eFb);
        hipLaunchKernelGGL(prep_apad_kernel, dim3(((int)eFa + 255) / 256), blk, 0, stream,
                           fatoms, 38, fatomsP, n_atoms, (int)eFa);

        const dim3 gB(Mb_b / 64), gA(Mb_a / 64), tpb(512);

        // X0 = q8(relu(fbonds @ W_i))
        hipLaunchKernelGGL((gemm_mfma_kernel<1>), gB, tpb, 0, stream,
                           fbondsP, (const unsigned short*)nullptr, WhcatT,
                           (const float*)nullptr, (unsigned short*)nullptr,
                           Xq, Xs, n_bonds, 2);
        // 4 iterations
        for (int it = 0; it < 4; ++it) {
            hipLaunchKernelGGL(gather_deq_kernel, dim3((n_bonds + 3) / 4), blk, 0, stream,
                               Xq, Xs, bgraph, nei, n_bonds);
            hipLaunchKernelGGL((gemm_mfma_kernel<1>), gB, tpb, 0, stream,
                               fbondsP, nei, WhcatT,
                               (const float*)nullptr, (unsigned short*)nullptr,
                               Xq, Xs, n_bonds, 16);
        }
        // atom readout: gather then bf16 GEMM written in-place over nei
        hipLaunchKernelGGL(gather_deq_kernel, dim3((n_atoms + 3) / 4), blk, 0, stream,
                           Xq, Xs, agraph, nei, n_atoms);
        hipLaunchKernelGGL((gemm_mfma_kernel<0>), gA, tpb, 0, stream,
                           fatomsP, nei, WocatT, b_o, nei,
                           (unsigned char*)nullptr, (float*)nullptr, n_atoms, 16);
        hipLaunchKernelGGL(segmean_kernel, dim3(n_mols), dim3(HIDDEN), 0, stream,
                           nei, mol_idx, (float*)d_out, n_atoms);
    } else {
        // diagnostic: absmax = 2272 + ws_MiB
        const float val = -(float)((double)ws_size / (1024.0 * 1024.0));
        hipLaunchKernelGGL(fill_kernel, dim3((out_size + 255) / 256), blk, 0, stream,
                           (float*)d_out, out_size, val);
    }
}